// Round 23
// baseline (62.983 us; speedup 1.0000x reference)
//
#include <hip/hip_runtime.h>
#include <hip/hip_bf16.h>

#define BB 2
#define SS 1024
#define DD 1024
#define HH 16
#define HDD 64
#define MASK_VAL -10000.0f
#define LOG2E 1.44269504f
#define BSD (BB * SS * DD)   // 2097152

typedef __attribute__((ext_vector_type(8))) short bf16x8;
typedef __attribute__((ext_vector_type(4))) short short4v;
typedef __attribute__((ext_vector_type(4))) float f32x4;
typedef __attribute__((ext_vector_type(16))) float f32x16;
typedef __attribute__((ext_vector_type(4))) unsigned int uint4v;

__device__ __forceinline__ short f2bf(float f) {
    union { float f; unsigned u; } v; v.f = f;
    unsigned r = v.u + 0x7FFFu + ((v.u >> 16) & 1u);   // RN-even
    return (short)(r >> 16);
}
__device__ __forceinline__ float bf2f(short s) {
    union { unsigned u; float f; } v;
    v.u = ((unsigned)(unsigned short)s) << 16;
    return v.f;
}
__device__ __forceinline__ unsigned cvt_pk_bf16(float lo, float hi) {
    unsigned r;
    asm("v_cvt_pk_bf16_f32 %0, %1, %2" : "=v"(r) : "v"(lo), "v"(hi));
    return r;
}
// bare v_exp_f32: computes 2^x (exp2 domain; log2e pre-folded into operands)
__device__ __forceinline__ float v_exp2(float x) {
    float r;
    asm("v_exp_f32 %0, %1" : "=v"(r) : "v"(x));
    return r;
}
__device__ __forceinline__ void plane32_swap(unsigned& a, unsigned& b) {
#if __has_builtin(__builtin_amdgcn_permlane32_swap)
    auto r = __builtin_amdgcn_permlane32_swap(a, b, false, false);
    a = r[0]; b = r[1];
#else
    unsigned as = (unsigned)__shfl_xor((int)a, 32);
    unsigned bs = (unsigned)__shfl_xor((int)b, 32);
    bool lo = ((threadIdx.x & 63) < 32);
    unsigned na = lo ? a : bs;
    unsigned nb = lo ? as : b;
    a = na; b = nb;
#endif
}

// ---------------------------------------------------------------------------
// fused prep, compact grid (3072 blocks)
// ---------------------------------------------------------------------------
__global__ __launch_bounds__(256) void k_prep(
    const float* __restrict__ h,
    const float* __restrict__ wq, const float* __restrict__ wk,
    const float* __restrict__ wv, const float* __restrict__ wo,
    short* __restrict__ xbf, short* __restrict__ wbf) {
    int id = blockIdx.x;
    if (id < 1024) {
        int i = id * 256 + threadIdx.x;
        const float4* h0 = (const float4*)h;
        const float4* h1 = (const float4*)(h + (size_t)BSD);
        float4 a0 = h0[2 * i], a1 = h0[2 * i + 1];
        float4 b0 = h1[2 * i], b1 = h1[2 * i + 1];
        bf16x8 o;
        o[0] = f2bf(a0.x + b0.x); o[1] = f2bf(a0.y + b0.y);
        o[2] = f2bf(a0.z + b0.z); o[3] = f2bf(a0.w + b0.w);
        o[4] = f2bf(a1.x + b1.x); o[5] = f2bf(a1.y + b1.y);
        o[6] = f2bf(a1.z + b1.z); o[7] = f2bf(a1.w + b1.w);
        ((bf16x8*)xbf)[i] = o;
    } else {
        int zi = (id - 1024) >> 9;
        int i = ((id - 1024) & 511) * 256 + threadIdx.x;
        const float* src = (zi == 0) ? wq : (zi == 1) ? wk : (zi == 2) ? wv : wo;
        short* dst = wbf + (size_t)zi * (DD * DD);
        const float4* s4 = (const float4*)src;
        float4 a0 = s4[2 * i], a1 = s4[2 * i + 1];
        bf16x8 o;
        o[0] = f2bf(a0.x); o[1] = f2bf(a0.y); o[2] = f2bf(a0.z); o[3] = f2bf(a0.w);
        o[4] = f2bf(a1.x); o[5] = f2bf(a1.y); o[6] = f2bf(a1.z); o[7] = f2bf(a1.w);
        ((bf16x8*)dst)[i] = o;
    }
}

// ---------------------------------------------------------------------------
// QKV bf16 MFMA GEMM — R14-exact: 128x64 tile, BK=64, XOR chunk-swizzled LDS.
// ---------------------------------------------------------------------------
#define QBM 128
#define QBN 64
#define QBK 64

__global__ __launch_bounds__(256) void k_gemm_qkv(
    const short* __restrict__ xbf, const short* __restrict__ wbf,
    const float* __restrict__ bq, const float* __restrict__ bk,
    const float* __restrict__ bv,
    short* __restrict__ qb, short* __restrict__ kb, short* __restrict__ vt) {
    __shared__ __align__(16) short As[QBM * QBK];   // 16 KB
    __shared__ __align__(16) short Bs[QBN * QBK];   // 8 KB
    const int z = blockIdx.z;
    const short* W = wbf + (size_t)z * (DD * DD);
    const float* bias = (z == 0) ? bq : (z == 1) ? bk : bv;
    const int bm = blockIdx.y * QBM;
    const int bn = blockIdx.x * QBN;
    const int tid = threadIdx.x;
    const int lane = tid & 63;
    const int wid = tid >> 6;
    const int wm = wid >> 1;
    const int wn = wid & 1;
    const int lr = lane & 15;
    const int kq = lane >> 4;

    f32x4 acc[4][2];
#pragma unroll
    for (int i = 0; i < 4; ++i)
#pragma unroll
        for (int j = 0; j < 2; ++j) acc[i][j] = (f32x4)0.0f;

    for (int k0 = 0; k0 < DD; k0 += QBK) {
#pragma unroll
        for (int i = 0; i < 4; ++i) {
            int s = i * 256 + tid;
            int r = s >> 3;
            int cs = (s & 7) ^ (r & 7);
            __builtin_amdgcn_global_load_lds(
                (const __attribute__((address_space(1))) unsigned*)(xbf + (size_t)(bm + r) * DD + k0 + (cs << 3)),
                (__attribute__((address_space(3))) unsigned*)&As[s * 8], 16, 0, 0);
        }
#pragma unroll
        for (int i = 0; i < 2; ++i) {
            int s = i * 256 + tid;
            int r = s >> 3;
            int cs = (s & 7) ^ (r & 7);
            __builtin_amdgcn_global_load_lds(
                (const __attribute__((address_space(1))) unsigned*)(W + (size_t)(bn + r) * DD + k0 + (cs << 3)),
                (__attribute__((address_space(3))) unsigned*)&Bs[s * 8], 16, 0, 0);
        }
        __syncthreads();

        bf16x8 af[4][2], bfr[2][2];
#pragma unroll
        for (int f = 0; f < 4; ++f) {
            int row = wm * 64 + f * 16 + lr;
#pragma unroll
            for (int ks = 0; ks < 2; ++ks) {
                int cpos = ((ks << 2) | kq) ^ (row & 7);
                af[f][ks] = *(const bf16x8*)&As[row * QBK + (cpos << 3)];
            }
        }
#pragma unroll
        for (int g = 0; g < 2; ++g) {
            int row = wn * 32 + g * 16 + lr;
#pragma unroll
            for (int ks = 0; ks < 2; ++ks) {
                int cpos = ((ks << 2) | kq) ^ (row & 7);
                bfr[g][ks] = *(const bf16x8*)&Bs[row * QBK + (cpos << 3)];
            }
        }
#pragma unroll
        for (int fm = 0; fm < 4; ++fm)
#pragma unroll
            for (int fn = 0; fn < 2; ++fn)
#pragma unroll
                for (int ks = 0; ks < 2; ++ks)
                    acc[fm][fn] = __builtin_amdgcn_mfma_f32_16x16x32_bf16(
                        af[fm][ks], bfr[fn][ks], acc[fm][fn], 0, 0, 0);
        __syncthreads();
    }

    if (z < 2) {
        short* C = (z == 0) ? qb : kb;
#pragma unroll
        for (int fm = 0; fm < 4; ++fm) {
            int row0 = bm + wm * 64 + fm * 16 + kq * 4;
#pragma unroll
            for (int fn = 0; fn < 2; ++fn) {
                int col = bn + wn * 32 + fn * 16 + lr;
                float bv_ = bias[col];
#pragma unroll
                for (int j = 0; j < 4; ++j)
                    C[(size_t)(row0 + j) * DD + col] = f2bf(acc[fm][fn][j] + bv_);
            }
        }
    } else {
#pragma unroll
        for (int fm = 0; fm < 4; ++fm) {
            int row0 = bm + wm * 64 + fm * 16 + kq * 4;
            int bidx = row0 >> 10, s0 = row0 & 1023;
#pragma unroll
            for (int fn = 0; fn < 2; ++fn) {
                int col = bn + wn * 32 + fn * 16 + lr;
                float bv_ = bias[col];
                size_t addr = ((size_t)(bidx * HH + (col >> 6)) * HDD + (col & 63)) * SS + s0;
                short4v o;
                o.x = f2bf(acc[fm][fn][0] + bv_); o.y = f2bf(acc[fm][fn][1] + bv_);
                o.z = f2bf(acc[fm][fn][2] + bv_); o.w = f2bf(acc[fm][fn][3] + bv_);
                *(short4v*)&vt[addr] = o;
            }
        }
    }
}

// ---------------------------------------------------------------------------
// Output GEMM — plain swizzled GEMM. 64x64 tile, BK=64, f32 out + bias.
// ---------------------------------------------------------------------------
#define OM 64
#define ON 64
#define OK 64

__global__ __launch_bounds__(256) void k_gemm_out(
    const short* __restrict__ A, const short* __restrict__ W,
    const float* __restrict__ bias, float* __restrict__ C) {
    __shared__ __align__(16) short As[OM * OK];   // 8 KB
    __shared__ __align__(16) short Bs[ON * OK];   // 8 KB
    const int bm = blockIdx.y * OM;
    const int bn = blockIdx.x * ON;
    const int tid = threadIdx.x;
    const int lane = tid & 63;
    const int wid = tid >> 6;
    const int wm = wid & 1;
    const int wn = wid >> 1;
    const int lr = lane & 15;
    const int kq = lane >> 4;

    f32x4 acc[2][2];
#pragma unroll
    for (int i = 0; i < 2; ++i)
#pragma unroll
        for (int j = 0; j < 2; ++j) acc[i][j] = (f32x4)0.0f;

    for (int k0 = 0; k0 < DD; k0 += OK) {
#pragma unroll
        for (int i = 0; i < 2; ++i) {
            int t2 = i * 256 + tid;
            int r = t2 >> 3;
            int cs = (t2 & 7) ^ (r & 7);
            __builtin_amdgcn_global_load_lds(
                (const __attribute__((address_space(1))) unsigned*)(A + (size_t)(bm + r) * DD + k0 + (cs << 3)),
                (__attribute__((address_space(3))) unsigned*)&As[t2 * 8], 16, 0, 0);
        }
#pragma unroll
        for (int i = 0; i < 2; ++i) {
            int t2 = i * 256 + tid;
            int r = t2 >> 3;
            int cs = (t2 & 7) ^ (r & 7);
            __builtin_amdgcn_global_load_lds(
                (const __attribute__((address_space(1))) unsigned*)(W + (size_t)(bn + r) * DD + k0 + (cs << 3)),
                (__attribute__((address_space(3))) unsigned*)&Bs[t2 * 8], 16, 0, 0);
        }
        __syncthreads();

        bf16x8 af[2][2], bfr[2][2];
#pragma unroll
        for (int f = 0; f < 2; ++f) {
            int rowa = wm * 32 + f * 16 + lr;
            int rowb = wn * 32 + f * 16 + lr;
#pragma unroll
            for (int ks = 0; ks < 2; ++ks) {
                int ca = (((ks << 2) | kq)) ^ (rowa & 7);
                int cb = (((ks << 2) | kq)) ^ (rowb & 7);
                af[f][ks] = *(const bf16x8*)&As[rowa * OK + (ca << 3)];
                bfr[f][ks] = *(const bf16x8*)&Bs[rowb * OK + (cb << 3)];
            }
        }
#pragma unroll
        for (int fm = 0; fm < 2; ++fm)
#pragma unroll
            for (int fn = 0; fn < 2; ++fn)
#pragma unroll
                for (int ks = 0; ks < 2; ++ks)
                    acc[fm][fn] = __builtin_amdgcn_mfma_f32_16x16x32_bf16(
                        af[fm][ks], bfr[fn][ks], acc[fm][fn], 0, 0, 0);
        __syncthreads();
    }

#pragma unroll
    for (int fm = 0; fm < 2; ++fm) {
        int row0 = bm + wm * 32 + fm * 16 + kq * 4;
#pragma unroll
        for (int fn = 0; fn < 2; ++fn) {
            int col = bn + wn * 32 + fn * 16 + lr;
            float bv_ = bias[col];
#pragma unroll
            for (int j = 0; j < 4; ++j)
                C[(size_t)(row0 + j) * DD + col] = acc[fm][fn][j] + bv_;
        }
    }
}

// ---------------------------------------------------------------------------
// MFMA flash attention — R22 structure (48 KB LDS: K dbuf + V single buffer,
// 3 blocks/CU) with RESTORED split K/V waits (R8/R19 discipline): the V-wait
// moves from the top-of-iter vmcnt into the body just before PV, so V(it)'s
// load latency hides under QK^T+softmax instead of being exposed.
// vmcnt audit (per-wave, issue order K(it), V(it), K(it+1)):
//   iter start after stageK(it+1): 12 outstanding -> K-wait vmcnt(8)
//   before PV: 8 outstanding -> V-wait vmcnt(4) (K(it+1) stays in flight)
//   post-PV barrier, stageV(it+1): back to 8.
//   tail it=7 (no stageK): K-wait vmcnt(4), V-wait vmcnt(0).
// ---------------------------------------------------------------------------
__global__ __launch_bounds__(256) void k_attn(
    const short* __restrict__ qb, const short* __restrict__ kb,
    const short* __restrict__ vt, const float* __restrict__ mask,
    short* __restrict__ ctx) {
    __shared__ __align__(16) short Kls[2][2][64 * 64];   // [kvh][dbuf] 32 KB
    __shared__ __align__(16) short Vls[2][64 * 64];      // [kvh] single 16 KB

    const int bh = blockIdx.x;           // bh fastest -> XCD = bh%8
    const int b = bh >> 4;
    const int h = bh & 15;
    const int q0 = blockIdx.y << 6;      // 64 q-rows per block
    const int tid = threadIdx.x;
    const int gtid = tid & 127;          // thread within kv-group (128 thr)
    const int kvh = tid >> 7;            // 0 or 1
    const int lane = tid & 63;
    const int w4 = (tid >> 6) & 1;       // q sub-tile within group (0..1)
    const int ql = lane & 31;
    const int hi = lane >> 5;
    const int rsw = ql & 7;
    const int tbase = kvh << 9;          // 0 or 512
    const float scale2 = 0.125f * LOG2E;
    const float mval2 = MASK_VAL * LOG2E;

    const short* khead = kb + (size_t)b * SS * DD + h * HDD;
    const short* vhead = vt + (size_t)bh * HDD * SS;
    const float* maskp = mask + b * SS;

    bf16x8 qf0, qf1, qf2, qf3;
    {
        const short* qrow = qb + ((size_t)(b * SS + q0 + w4 * 32 + ql)) * DD + h * HDD + hi * 8;
        qf0 = *(const bf16x8*)(qrow);
        qf1 = *(const bf16x8*)(qrow + 16);
        qf2 = *(const bf16x8*)(qrow + 32);
        qf3 = *(const bf16x8*)(qrow + 48);
    }

    // stage K tile (64 rows): 4 gload_lds/thread, 128 threads/group
    auto stageK = [&](int t0, int bi) {
        const short* kbase = khead + (size_t)t0 * DD;
#pragma unroll
        for (int i = 0; i < 4; ++i) {
            int t = i * 128 + gtid;       // 0..511 chunks
            int r = t >> 3;
            int cs = (t & 7) ^ (r & 7);
            __builtin_amdgcn_global_load_lds(
                (const __attribute__((address_space(1))) unsigned*)(kbase + (size_t)r * DD + cs * 8),
                (__attribute__((address_space(3))) unsigned*)&Kls[kvh][bi][t * 8], 16, 0, 0);
        }
    };
    // stage V tile into the SINGLE V buffer
    auto stageV = [&](int t0) {
        const short* vbase = vhead + t0;
#pragma unroll
        for (int i = 0; i < 4; ++i) {
            int t = i * 128 + gtid;
            int r = t >> 3;
            int cs = (t & 7) ^ (r & 7);
            __builtin_amdgcn_global_load_lds(
                (const __attribute__((address_space(1))) unsigned*)(vbase + (size_t)r * SS + cs * 8),
                (__attribute__((address_space(3))) unsigned*)&Vls[kvh][t * 8], 16, 0, 0);
        }
    };

    float m_r = -3.0e38f, l_r = 0.0f;
    f32x16 O0 = (f32x16)0.0f, O1 = (f32x16)0.0f;

    auto body = [&](int t0, int cur, int tail) {
        const short* Kb = &Kls[kvh][cur][0];
        const short* Vb = &Vls[kvh][0];

        f32x16 s0 = (f32x16)0.0f, s1 = (f32x16)0.0f;
        __builtin_amdgcn_s_setprio(1);
#pragma unroll
        for (int step = 0; step < 4; ++step) {
            int cpos = ((step << 1) | hi) ^ rsw;
            bf16x8 k0 = *(const bf16x8*)&Kb[ql * 64 + (cpos << 3)];
            bf16x8 k1 = *(const bf16x8*)&Kb[(32 + ql) * 64 + (cpos << 3)];
            bf16x8 qf = (step == 0) ? qf0 : (step == 1) ? qf1 : (step == 2) ? qf2 : qf3;
            s0 = __builtin_amdgcn_mfma_f32_32x32x16_bf16(k0, qf, s0, 0, 0, 0);
            s1 = __builtin_amdgcn_mfma_f32_32x32x16_bf16(k1, qf, s1, 0, 0, 0);
        }
        __builtin_amdgcn_s_setprio(0);

#pragma unroll
        for (int g = 0; g < 4; ++g) {
            float4 a4 = *(const float4*)&maskp[t0 + 8 * g + 4 * hi];
            float4 b4 = *(const float4*)&maskp[t0 + 32 + 8 * g + 4 * hi];
            s0[4 * g + 0] = fmaf(s0[4 * g + 0], scale2, (1.0f - a4.x) * mval2);
            s0[4 * g + 1] = fmaf(s0[4 * g + 1], scale2, (1.0f - a4.y) * mval2);
            s0[4 * g + 2] = fmaf(s0[4 * g + 2], scale2, (1.0f - a4.z) * mval2);
            s0[4 * g + 3] = fmaf(s0[4 * g + 3], scale2, (1.0f - a4.w) * mval2);
            s1[4 * g + 0] = fmaf(s1[4 * g + 0], scale2, (1.0f - b4.x) * mval2);
            s1[4 * g + 1] = fmaf(s1[4 * g + 1], scale2, (1.0f - b4.y) * mval2);
            s1[4 * g + 2] = fmaf(s1[4 * g + 2], scale2, (1.0f - b4.z) * mval2);
            s1[4 * g + 3] = fmaf(s1[4 * g + 3], scale2, (1.0f - b4.w) * mval2);
        }

        float mt[16];
#pragma unroll
        for (int r = 0; r < 16; ++r) mt[r] = fmaxf(s0[r], s1[r]);
#pragma unroll
        for (int st = 8; st > 0; st >>= 1)
#pragma unroll
            for (int r = 0; r < 8; ++r)
                if (r < st) mt[r] = fmaxf(mt[r], mt[r + st]);
        float mx = fmaxf(mt[0], __shfl_xor(mt[0], 32));

        bool need = mx > m_r + 8.0f;   // exp2 domain: P bounded by 2^8
        if (__any(need)) {
            float mn = fmaxf(m_r, mx);
            float alpha = v_exp2(m_r - mn);
            m_r = mn;
            l_r *= alpha;
#pragma unroll
            for (int r = 0; r < 16; ++r) {
                int qrow = (r & 3) + 8 * (r >> 2) + 4 * hi;
                float al = __shfl(alpha, qrow, 64);
                O0[r] *= al;
                O1[r] *= al;
            }
        }

        float st0[16];
#pragma unroll
        for (int r = 0; r < 16; ++r) {
            s0[r] = v_exp2(s0[r] - m_r);
            s1[r] = v_exp2(s1[r] - m_r);
            st0[r] = s0[r] + s1[r];
        }
#pragma unroll
        for (int st = 8; st > 0; st >>= 1)
#pragma unroll
            for (int r = 0; r < 8; ++r)
                if (r < st) st0[r] += st0[r + st];
        l_r += st0[0] + __shfl_xor(st0[0], 32);

        unsigned w0 = cvt_pk_bf16(s0[0], s0[1]),  w1 = cvt_pk_bf16(s0[2], s0[3]);
        unsigned w2 = cvt_pk_bf16(s0[4], s0[5]),  w3 = cvt_pk_bf16(s0[6], s0[7]);
        unsigned w4_ = cvt_pk_bf16(s0[8], s0[9]),  w5 = cvt_pk_bf16(s0[10], s0[11]);
        unsigned w6 = cvt_pk_bf16(s0[12], s0[13]), w7 = cvt_pk_bf16(s0[14], s0[15]);
        plane32_swap(w0, w2); plane32_swap(w1, w3);
        plane32_swap(w4_, w6); plane32_swap(w5, w7);
        uint4v f0 = {w0, w1, w2, w3};
        uint4v f1 = {w4_, w5, w6, w7};
        unsigned x0 = cvt_pk_bf16(s1[0], s1[1]),  x1 = cvt_pk_bf16(s1[2], s1[3]);
        unsigned x2 = cvt_pk_bf16(s1[4], s1[5]),  x3 = cvt_pk_bf16(s1[6], s1[7]);
        unsigned x4 = cvt_pk_bf16(s1[8], s1[9]),  x5 = cvt_pk_bf16(s1[10], s1[11]);
        unsigned x6 = cvt_pk_bf16(s1[12], s1[13]), x7 = cvt_pk_bf16(s1[14], s1[15]);
        plane32_swap(x0, x2); plane32_swap(x1, x3);
        plane32_swap(x4, x6); plane32_swap(x5, x7);
        uint4v f2 = {x0, x1, x2, x3};
        uint4v f3 = {x4, x5, x6, x7};

        bf16x8 pf0 = __builtin_bit_cast(bf16x8, f0);
        bf16x8 pf1 = __builtin_bit_cast(bf16x8, f1);
        bf16x8 pf2 = __builtin_bit_cast(bf16x8, f2);
        bf16x8 pf3 = __builtin_bit_cast(bf16x8, f3);

        // V(it) ready gate — V latency hid under QK^T+softmax above
        if (tail) { asm volatile("s_waitcnt vmcnt(0)\n\ts_barrier" ::: "memory"); }
        else      { asm volatile("s_waitcnt vmcnt(4)\n\ts_barrier" ::: "memory"); }

        __builtin_amdgcn_s_setprio(1);
#pragma unroll
        for (int ks = 0; ks < 4; ++ks) {
            int cpos = ((ks << 1) | hi) ^ rsw;
            bf16x8 pf = (ks == 0) ? pf0 : (ks == 1) ? pf1 : (ks == 2) ? pf2 : pf3;
            bf16x8 v0 = *(const bf16x8*)&Vb[ql * 64 + (cpos << 3)];
            bf16x8 v1 = *(const bf16x8*)&Vb[(32 + ql) * 64 + (cpos << 3)];
            O0 = __builtin_amdgcn_mfma_f32_32x32x16_bf16(pf, v0, O0, 0, 0, 0);
            O1 = __builtin_amdgcn_mfma_f32_32x32x16_bf16(pf, v1, O1, 0, 0, 0);
        }
        __builtin_amdgcn_s_setprio(0);
    };

    // prologue: K(0) + V(0)
    stageK(tbase, 0);
    stageV(tbase);
#pragma unroll 1
    for (int it = 0; it < 8; ++it) {
        if (it < 7) {
            stageK(tbase + ((it + 1) << 6), (it + 1) & 1);
            asm volatile("s_waitcnt vmcnt(8)\n\ts_barrier" ::: "memory");  // K(it) ready
        } else {
            asm volatile("s_waitcnt vmcnt(4)\n\ts_barrier" ::: "memory");  // K(7) ready
        }
        body(tbase + (it << 6), it & 1, it == 7);
        __builtin_amdgcn_s_barrier();          // all waves done reading V(it)/K(it)
        if (it < 7) stageV(tbase + ((it + 1) << 6));
    }

    // ---- in-LDS fp32 merge of the two kv-halves ----
    __syncthreads();                                   // all K/V reads done
    float* osh = (float*)&Kls[0][0][0];                // 2 x 2048 floats (16 KB)
    float* mlsh = (float*)&Vls[0][0];                  // 2 x 64 floats
    if (kvh == 1) {
        float* obuf = osh + w4 * 2048;
#pragma unroll
        for (int r = 0; r < 16; ++r) {
            int qrow = (r & 3) + 8 * (r >> 2) + 4 * hi;
            obuf[qrow * 64 + ql] = O0[r];
            obuf[qrow * 64 + 32 + ql] = O1[r];
        }
        if (lane < 32) {
            mlsh[w4 * 64 + ql] = m_r;
            mlsh[w4 * 64 + 32 + ql] = l_r;
        }
    }
    __syncthreads();
    if (kvh == 0) {
        float* obuf = osh + w4 * 2048;
        float m2 = mlsh[w4 * 64 + ql];
        float l2 = mlsh[w4 * 64 + 32 + ql];
        float m = fmaxf(m_r, m2);
        float a1 = v_exp2(m_r - m), a2 = v_exp2(m2 - m);
        float inv = 1.0f / (l_r * a1 + l2 * a2);
        float c1 = a1 * inv, c2 = a2 * inv;
        short* cb = ctx + ((size_t)(b * SS + q0 + w4 * 32)) * DD + h * HDD;
#pragma unroll
        for (int r = 0; r < 16; ++r) {
            int qrow = (r & 3) + 8 * (r >> 2) + 4 * hi;
            float cc1 = __shfl(c1, qrow, 64);
            float cc2 = __shfl(c2, qrow, 64);
            float ob0 = obuf[qrow * 64 + ql];
            float ob1 = obuf[qrow * 64 + 32 + ql];
            cb[(size_t)qrow * DD + ql]      = f2bf(O0[r] * cc1 + ob0 * cc2);
            cb[(size_t)qrow * DD + 32 + ql] = f2bf(O1[r] * cc1 + ob1 * cc2);
        }
    }
}

// ---------------------------------------------------------------------------
extern "C" void kernel_launch(void* const* d_in, const int* in_sizes, int n_in,
                              void* d_out, int out_size, void* d_ws, size_t ws_size,
                              hipStream_t stream) {
    const float* h    = (const float*)d_in[0];
    const float* mask = (const float*)d_in[1];
    const float* wq   = (const float*)d_in[2];
    const float* bq   = (const float*)d_in[3];
    const float* wk   = (const float*)d_in[4];
    const float* bk   = (const float*)d_in[5];
    const float* wv   = (const float*)d_in[6];
    const float* bv   = (const float*)d_in[7];
    const float* wo   = (const float*)d_in[8];
    const float* bo   = (const float*)d_in[9];
    float* out = (float*)d_out;

    char* base = (char*)d_ws;
    short* x_bf  = (short*)base;                       // 4 MB @ 0
    short* w_bf  = (short*)(base + (4u << 20));        // 8 MB @ 4
    short* q_bf  = (short*)(base + (12u << 20));       // 4 MB @ 12
    short* k_bf  = (short*)(base + (16u << 20));       // 4 MB @ 16
    short* v_t   = (short*)(base + (20u << 20));       // 4 MB @ 20
    short* ctxbf = (short*)(base + (24u << 20));       // 4 MB @ 24

    k_prep<<<3072, 256, 0, stream>>>(h, wq, wk, wv, wo, x_bf, w_bf);

    dim3 gqkv(DD / QBN, BB * SS / QBM, 3);
    k_gemm_qkv<<<gqkv, 256, 0, stream>>>(x_bf, w_bf, bq, bk, bv, q_bf, k_bf, v_t);

    dim3 gattn(BB * HH, SS / 64);    // bh fastest -> XCD locality; 512 blocks
    k_attn<<<gattn, 256, 0, stream>>>(q_bf, k_bf, v_t, mask, ctxbf);

    dim3 gout(DD / ON, BB * SS / OM);
    k_gemm_out<<<gout, 256, 0, stream>>>(ctxbf, w_bf + (size_t)3 * DD * DD, bo, out);
}

// Round 24
// 62.596 us; speedup vs baseline: 1.0062x; 1.0062x over previous
//
#include <hip/hip_runtime.h>
#include <hip/hip_bf16.h>

#define BB 2
#define SS 1024
#define DD 1024
#define HH 16
#define HDD 64
#define MASK_VAL -10000.0f
#define LOG2E 1.44269504f
#define BSD (BB * SS * DD)   // 2097152

typedef __attribute__((ext_vector_type(8))) short bf16x8;
typedef __attribute__((ext_vector_type(4))) short short4v;
typedef __attribute__((ext_vector_type(4))) float f32x4;
typedef __attribute__((ext_vector_type(16))) float f32x16;
typedef __attribute__((ext_vector_type(4))) unsigned int uint4v;

__device__ __forceinline__ short f2bf(float f) {
    union { float f; unsigned u; } v; v.f = f;
    unsigned r = v.u + 0x7FFFu + ((v.u >> 16) & 1u);   // RN-even
    return (short)(r >> 16);
}
__device__ __forceinline__ float bf2f(short s) {
    union { unsigned u; float f; } v;
    v.u = ((unsigned)(unsigned short)s) << 16;
    return v.f;
}
__device__ __forceinline__ unsigned cvt_pk_bf16(float lo, float hi) {
    unsigned r;
    asm("v_cvt_pk_bf16_f32 %0, %1, %2" : "=v"(r) : "v"(lo), "v"(hi));
    return r;
}
// bare v_exp_f32: computes 2^x (exp2 domain; log2e pre-folded into operands)
__device__ __forceinline__ float v_exp2(float x) {
    float r;
    asm("v_exp_f32 %0, %1" : "=v"(r) : "v"(x));
    return r;
}
__device__ __forceinline__ void plane32_swap(unsigned& a, unsigned& b) {
#if __has_builtin(__builtin_amdgcn_permlane32_swap)
    auto r = __builtin_amdgcn_permlane32_swap(a, b, false, false);
    a = r[0]; b = r[1];
#else
    unsigned as = (unsigned)__shfl_xor((int)a, 32);
    unsigned bs = (unsigned)__shfl_xor((int)b, 32);
    bool lo = ((threadIdx.x & 63) < 32);
    unsigned na = lo ? a : bs;
    unsigned nb = lo ? as : b;
    a = na; b = nb;
#endif
}

// ---------------------------------------------------------------------------
// fused prep, compact grid (3072 blocks)
// ---------------------------------------------------------------------------
__global__ __launch_bounds__(256) void k_prep(
    const float* __restrict__ h,
    const float* __restrict__ wq, const float* __restrict__ wk,
    const float* __restrict__ wv, const float* __restrict__ wo,
    short* __restrict__ xbf, short* __restrict__ wbf) {
    int id = blockIdx.x;
    if (id < 1024) {
        int i = id * 256 + threadIdx.x;
        const float4* h0 = (const float4*)h;
        const float4* h1 = (const float4*)(h + (size_t)BSD);
        float4 a0 = h0[2 * i], a1 = h0[2 * i + 1];
        float4 b0 = h1[2 * i], b1 = h1[2 * i + 1];
        bf16x8 o;
        o[0] = f2bf(a0.x + b0.x); o[1] = f2bf(a0.y + b0.y);
        o[2] = f2bf(a0.z + b0.z); o[3] = f2bf(a0.w + b0.w);
        o[4] = f2bf(a1.x + b1.x); o[5] = f2bf(a1.y + b1.y);
        o[6] = f2bf(a1.z + b1.z); o[7] = f2bf(a1.w + b1.w);
        ((bf16x8*)xbf)[i] = o;
    } else {
        int zi = (id - 1024) >> 9;
        int i = ((id - 1024) & 511) * 256 + threadIdx.x;
        const float* src = (zi == 0) ? wq : (zi == 1) ? wk : (zi == 2) ? wv : wo;
        short* dst = wbf + (size_t)zi * (DD * DD);
        const float4* s4 = (const float4*)src;
        float4 a0 = s4[2 * i], a1 = s4[2 * i + 1];
        bf16x8 o;
        o[0] = f2bf(a0.x); o[1] = f2bf(a0.y); o[2] = f2bf(a0.z); o[3] = f2bf(a0.w);
        o[4] = f2bf(a1.x); o[5] = f2bf(a1.y); o[6] = f2bf(a1.z); o[7] = f2bf(a1.w);
        ((bf16x8*)dst)[i] = o;
    }
}

// ---------------------------------------------------------------------------
// QKV bf16 MFMA GEMM — R14-exact: 128x64 tile, BK=64, XOR chunk-swizzled LDS.
// ---------------------------------------------------------------------------
#define QBM 128
#define QBN 64
#define QBK 64

__global__ __launch_bounds__(256) void k_gemm_qkv(
    const short* __restrict__ xbf, const short* __restrict__ wbf,
    const float* __restrict__ bq, const float* __restrict__ bk,
    const float* __restrict__ bv,
    short* __restrict__ qb, short* __restrict__ kb, short* __restrict__ vt) {
    __shared__ __align__(16) short As[QBM * QBK];   // 16 KB
    __shared__ __align__(16) short Bs[QBN * QBK];   // 8 KB
    const int z = blockIdx.z;
    const short* W = wbf + (size_t)z * (DD * DD);
    const float* bias = (z == 0) ? bq : (z == 1) ? bk : bv;
    const int bm = blockIdx.y * QBM;
    const int bn = blockIdx.x * QBN;
    const int tid = threadIdx.x;
    const int lane = tid & 63;
    const int wid = tid >> 6;
    const int wm = wid >> 1;
    const int wn = wid & 1;
    const int lr = lane & 15;
    const int kq = lane >> 4;

    f32x4 acc[4][2];
#pragma unroll
    for (int i = 0; i < 4; ++i)
#pragma unroll
        for (int j = 0; j < 2; ++j) acc[i][j] = (f32x4)0.0f;

    for (int k0 = 0; k0 < DD; k0 += QBK) {
#pragma unroll
        for (int i = 0; i < 4; ++i) {
            int s = i * 256 + tid;
            int r = s >> 3;
            int cs = (s & 7) ^ (r & 7);
            __builtin_amdgcn_global_load_lds(
                (const __attribute__((address_space(1))) unsigned*)(xbf + (size_t)(bm + r) * DD + k0 + (cs << 3)),
                (__attribute__((address_space(3))) unsigned*)&As[s * 8], 16, 0, 0);
        }
#pragma unroll
        for (int i = 0; i < 2; ++i) {
            int s = i * 256 + tid;
            int r = s >> 3;
            int cs = (s & 7) ^ (r & 7);
            __builtin_amdgcn_global_load_lds(
                (const __attribute__((address_space(1))) unsigned*)(W + (size_t)(bn + r) * DD + k0 + (cs << 3)),
                (__attribute__((address_space(3))) unsigned*)&Bs[s * 8], 16, 0, 0);
        }
        __syncthreads();

        bf16x8 af[4][2], bfr[2][2];
#pragma unroll
        for (int f = 0; f < 4; ++f) {
            int row = wm * 64 + f * 16 + lr;
#pragma unroll
            for (int ks = 0; ks < 2; ++ks) {
                int cpos = ((ks << 2) | kq) ^ (row & 7);
                af[f][ks] = *(const bf16x8*)&As[row * QBK + (cpos << 3)];
            }
        }
#pragma unroll
        for (int g = 0; g < 2; ++g) {
            int row = wn * 32 + g * 16 + lr;
#pragma unroll
            for (int ks = 0; ks < 2; ++ks) {
                int cpos = ((ks << 2) | kq) ^ (row & 7);
                bfr[g][ks] = *(const bf16x8*)&Bs[row * QBK + (cpos << 3)];
            }
        }
#pragma unroll
        for (int fm = 0; fm < 4; ++fm)
#pragma unroll
            for (int fn = 0; fn < 2; ++fn)
#pragma unroll
                for (int ks = 0; ks < 2; ++ks)
                    acc[fm][fn] = __builtin_amdgcn_mfma_f32_16x16x32_bf16(
                        af[fm][ks], bfr[fn][ks], acc[fm][fn], 0, 0, 0);
        __syncthreads();
    }

    if (z < 2) {
        short* C = (z == 0) ? qb : kb;
#pragma unroll
        for (int fm = 0; fm < 4; ++fm) {
            int row0 = bm + wm * 64 + fm * 16 + kq * 4;
#pragma unroll
            for (int fn = 0; fn < 2; ++fn) {
                int col = bn + wn * 32 + fn * 16 + lr;
                float bv_ = bias[col];
#pragma unroll
                for (int j = 0; j < 4; ++j)
                    C[(size_t)(row0 + j) * DD + col] = f2bf(acc[fm][fn][j] + bv_);
            }
        }
    } else {
#pragma unroll
        for (int fm = 0; fm < 4; ++fm) {
            int row0 = bm + wm * 64 + fm * 16 + kq * 4;
            int bidx = row0 >> 10, s0 = row0 & 1023;
#pragma unroll
            for (int fn = 0; fn < 2; ++fn) {
                int col = bn + wn * 32 + fn * 16 + lr;
                float bv_ = bias[col];
                size_t addr = ((size_t)(bidx * HH + (col >> 6)) * HDD + (col & 63)) * SS + s0;
                short4v o;
                o.x = f2bf(acc[fm][fn][0] + bv_); o.y = f2bf(acc[fm][fn][1] + bv_);
                o.z = f2bf(acc[fm][fn][2] + bv_); o.w = f2bf(acc[fm][fn][3] + bv_);
                *(short4v*)&vt[addr] = o;
            }
        }
    }
}

// ---------------------------------------------------------------------------
// Output GEMM — plain swizzled GEMM. 64x64 tile, BK=64, f32 out + bias.
// ---------------------------------------------------------------------------
#define OM 64
#define ON 64
#define OK 64

__global__ __launch_bounds__(256) void k_gemm_out(
    const short* __restrict__ A, const short* __restrict__ W,
    const float* __restrict__ bias, float* __restrict__ C) {
    __shared__ __align__(16) short As[OM * OK];   // 8 KB
    __shared__ __align__(16) short Bs[ON * OK];   // 8 KB
    const int bm = blockIdx.y * OM;
    const int bn = blockIdx.x * ON;
    const int tid = threadIdx.x;
    const int lane = tid & 63;
    const int wid = tid >> 6;
    const int wm = wid & 1;
    const int wn = wid >> 1;
    const int lr = lane & 15;
    const int kq = lane >> 4;

    f32x4 acc[2][2];
#pragma unroll
    for (int i = 0; i < 2; ++i)
#pragma unroll
        for (int j = 0; j < 2; ++j) acc[i][j] = (f32x4)0.0f;

    for (int k0 = 0; k0 < DD; k0 += OK) {
#pragma unroll
        for (int i = 0; i < 2; ++i) {
            int t2 = i * 256 + tid;
            int r = t2 >> 3;
            int cs = (t2 & 7) ^ (r & 7);
            __builtin_amdgcn_global_load_lds(
                (const __attribute__((address_space(1))) unsigned*)(A + (size_t)(bm + r) * DD + k0 + (cs << 3)),
                (__attribute__((address_space(3))) unsigned*)&As[t2 * 8], 16, 0, 0);
        }
#pragma unroll
        for (int i = 0; i < 2; ++i) {
            int t2 = i * 256 + tid;
            int r = t2 >> 3;
            int cs = (t2 & 7) ^ (r & 7);
            __builtin_amdgcn_global_load_lds(
                (const __attribute__((address_space(1))) unsigned*)(W + (size_t)(bn + r) * DD + k0 + (cs << 3)),
                (__attribute__((address_space(3))) unsigned*)&Bs[t2 * 8], 16, 0, 0);
        }
        __syncthreads();

        bf16x8 af[2][2], bfr[2][2];
#pragma unroll
        for (int f = 0; f < 2; ++f) {
            int rowa = wm * 32 + f * 16 + lr;
            int rowb = wn * 32 + f * 16 + lr;
#pragma unroll
            for (int ks = 0; ks < 2; ++ks) {
                int ca = (((ks << 2) | kq)) ^ (rowa & 7);
                int cb = (((ks << 2) | kq)) ^ (rowb & 7);
                af[f][ks] = *(const bf16x8*)&As[rowa * OK + (ca << 3)];
                bfr[f][ks] = *(const bf16x8*)&Bs[rowb * OK + (cb << 3)];
            }
        }
#pragma unroll
        for (int fm = 0; fm < 2; ++fm)
#pragma unroll
            for (int fn = 0; fn < 2; ++fn)
#pragma unroll
                for (int ks = 0; ks < 2; ++ks)
                    acc[fm][fn] = __builtin_amdgcn_mfma_f32_16x16x32_bf16(
                        af[fm][ks], bfr[fn][ks], acc[fm][fn], 0, 0, 0);
        __syncthreads();
    }

#pragma unroll
    for (int fm = 0; fm < 2; ++fm) {
        int row0 = bm + wm * 32 + fm * 16 + kq * 4;
#pragma unroll
        for (int fn = 0; fn < 2; ++fn) {
            int col = bn + wn * 32 + fn * 16 + lr;
            float bv_ = bias[col];
#pragma unroll
            for (int j = 0; j < 4; ++j)
                C[(size_t)(row0 + j) * DD + col] = acc[fm][fn][j] + bv_;
        }
    }
}

// ---------------------------------------------------------------------------
// MFMA flash attention — R22-exact (best measured, 62.8 µs total):
// 48 KB LDS (K dbuf + V single buffer) -> 3 blocks/CU; combined vmcnt(4)
// per-tile wait; post-PV barrier then stageV(it+1); bh-fastest grid for
// XCD locality; in-LDS fp32 merge of the kv halves.
// ---------------------------------------------------------------------------
__global__ __launch_bounds__(256) void k_attn(
    const short* __restrict__ qb, const short* __restrict__ kb,
    const short* __restrict__ vt, const float* __restrict__ mask,
    short* __restrict__ ctx) {
    __shared__ __align__(16) short Kls[2][2][64 * 64];   // [kvh][dbuf] 32 KB
    __shared__ __align__(16) short Vls[2][64 * 64];      // [kvh] single 16 KB

    const int bh = blockIdx.x;           // bh fastest -> XCD = bh%8
    const int b = bh >> 4;
    const int h = bh & 15;
    const int q0 = blockIdx.y << 6;      // 64 q-rows per block
    const int tid = threadIdx.x;
    const int gtid = tid & 127;          // thread within kv-group (128 thr)
    const int kvh = tid >> 7;            // 0 or 1
    const int lane = tid & 63;
    const int w4 = (tid >> 6) & 1;       // q sub-tile within group (0..1)
    const int ql = lane & 31;
    const int hi = lane >> 5;
    const int rsw = ql & 7;
    const int tbase = kvh << 9;          // 0 or 512
    const float scale2 = 0.125f * LOG2E;
    const float mval2 = MASK_VAL * LOG2E;

    const short* khead = kb + (size_t)b * SS * DD + h * HDD;
    const short* vhead = vt + (size_t)bh * HDD * SS;
    const float* maskp = mask + b * SS;

    bf16x8 qf0, qf1, qf2, qf3;
    {
        const short* qrow = qb + ((size_t)(b * SS + q0 + w4 * 32 + ql)) * DD + h * HDD + hi * 8;
        qf0 = *(const bf16x8*)(qrow);
        qf1 = *(const bf16x8*)(qrow + 16);
        qf2 = *(const bf16x8*)(qrow + 32);
        qf3 = *(const bf16x8*)(qrow + 48);
    }

    // stage K tile (64 rows): 4 gload_lds/thread, 128 threads/group
    auto stageK = [&](int t0, int bi) {
        const short* kbase = khead + (size_t)t0 * DD;
#pragma unroll
        for (int i = 0; i < 4; ++i) {
            int t = i * 128 + gtid;       // 0..511 chunks
            int r = t >> 3;
            int cs = (t & 7) ^ (r & 7);
            __builtin_amdgcn_global_load_lds(
                (const __attribute__((address_space(1))) unsigned*)(kbase + (size_t)r * DD + cs * 8),
                (__attribute__((address_space(3))) unsigned*)&Kls[kvh][bi][t * 8], 16, 0, 0);
        }
    };
    // stage V tile into the SINGLE V buffer
    auto stageV = [&](int t0) {
        const short* vbase = vhead + t0;
#pragma unroll
        for (int i = 0; i < 4; ++i) {
            int t = i * 128 + gtid;
            int r = t >> 3;
            int cs = (t & 7) ^ (r & 7);
            __builtin_amdgcn_global_load_lds(
                (const __attribute__((address_space(1))) unsigned*)(vbase + (size_t)r * SS + cs * 8),
                (__attribute__((address_space(3))) unsigned*)&Vls[kvh][t * 8], 16, 0, 0);
        }
    };

    float m_r = -3.0e38f, l_r = 0.0f;
    f32x16 O0 = (f32x16)0.0f, O1 = (f32x16)0.0f;

    auto body = [&](int t0, int cur) {
        const short* Kb = &Kls[kvh][cur][0];
        const short* Vb = &Vls[kvh][0];

        f32x16 s0 = (f32x16)0.0f, s1 = (f32x16)0.0f;
        __builtin_amdgcn_s_setprio(1);
#pragma unroll
        for (int step = 0; step < 4; ++step) {
            int cpos = ((step << 1) | hi) ^ rsw;
            bf16x8 k0 = *(const bf16x8*)&Kb[ql * 64 + (cpos << 3)];
            bf16x8 k1 = *(const bf16x8*)&Kb[(32 + ql) * 64 + (cpos << 3)];
            bf16x8 qf = (step == 0) ? qf0 : (step == 1) ? qf1 : (step == 2) ? qf2 : qf3;
            s0 = __builtin_amdgcn_mfma_f32_32x32x16_bf16(k0, qf, s0, 0, 0, 0);
            s1 = __builtin_amdgcn_mfma_f32_32x32x16_bf16(k1, qf, s1, 0, 0, 0);
        }
        __builtin_amdgcn_s_setprio(0);

#pragma unroll
        for (int g = 0; g < 4; ++g) {
            float4 a4 = *(const float4*)&maskp[t0 + 8 * g + 4 * hi];
            float4 b4 = *(const float4*)&maskp[t0 + 32 + 8 * g + 4 * hi];
            s0[4 * g + 0] = fmaf(s0[4 * g + 0], scale2, (1.0f - a4.x) * mval2);
            s0[4 * g + 1] = fmaf(s0[4 * g + 1], scale2, (1.0f - a4.y) * mval2);
            s0[4 * g + 2] = fmaf(s0[4 * g + 2], scale2, (1.0f - a4.z) * mval2);
            s0[4 * g + 3] = fmaf(s0[4 * g + 3], scale2, (1.0f - a4.w) * mval2);
            s1[4 * g + 0] = fmaf(s1[4 * g + 0], scale2, (1.0f - b4.x) * mval2);
            s1[4 * g + 1] = fmaf(s1[4 * g + 1], scale2, (1.0f - b4.y) * mval2);
            s1[4 * g + 2] = fmaf(s1[4 * g + 2], scale2, (1.0f - b4.z) * mval2);
            s1[4 * g + 3] = fmaf(s1[4 * g + 3], scale2, (1.0f - b4.w) * mval2);
        }

        float mt[16];
#pragma unroll
        for (int r = 0; r < 16; ++r) mt[r] = fmaxf(s0[r], s1[r]);
#pragma unroll
        for (int st = 8; st > 0; st >>= 1)
#pragma unroll
            for (int r = 0; r < 8; ++r)
                if (r < st) mt[r] = fmaxf(mt[r], mt[r + st]);
        float mx = fmaxf(mt[0], __shfl_xor(mt[0], 32));

        bool need = mx > m_r + 8.0f;   // exp2 domain: P bounded by 2^8
        if (__any(need)) {
            float mn = fmaxf(m_r, mx);
            float alpha = v_exp2(m_r - mn);
            m_r = mn;
            l_r *= alpha;
#pragma unroll
            for (int r = 0; r < 16; ++r) {
                int qrow = (r & 3) + 8 * (r >> 2) + 4 * hi;
                float al = __shfl(alpha, qrow, 64);
                O0[r] *= al;
                O1[r] *= al;
            }
        }

        float st0[16];
#pragma unroll
        for (int r = 0; r < 16; ++r) {
            s0[r] = v_exp2(s0[r] - m_r);
            s1[r] = v_exp2(s1[r] - m_r);
            st0[r] = s0[r] + s1[r];
        }
#pragma unroll
        for (int st = 8; st > 0; st >>= 1)
#pragma unroll
            for (int r = 0; r < 8; ++r)
                if (r < st) st0[r] += st0[r + st];
        l_r += st0[0] + __shfl_xor(st0[0], 32);

        unsigned w0 = cvt_pk_bf16(s0[0], s0[1]),  w1 = cvt_pk_bf16(s0[2], s0[3]);
        unsigned w2 = cvt_pk_bf16(s0[4], s0[5]),  w3 = cvt_pk_bf16(s0[6], s0[7]);
        unsigned w4_ = cvt_pk_bf16(s0[8], s0[9]),  w5 = cvt_pk_bf16(s0[10], s0[11]);
        unsigned w6 = cvt_pk_bf16(s0[12], s0[13]), w7 = cvt_pk_bf16(s0[14], s0[15]);
        plane32_swap(w0, w2); plane32_swap(w1, w3);
        plane32_swap(w4_, w6); plane32_swap(w5, w7);
        uint4v f0 = {w0, w1, w2, w3};
        uint4v f1 = {w4_, w5, w6, w7};
        unsigned x0 = cvt_pk_bf16(s1[0], s1[1]),  x1 = cvt_pk_bf16(s1[2], s1[3]);
        unsigned x2 = cvt_pk_bf16(s1[4], s1[5]),  x3 = cvt_pk_bf16(s1[6], s1[7]);
        unsigned x4 = cvt_pk_bf16(s1[8], s1[9]),  x5 = cvt_pk_bf16(s1[10], s1[11]);
        unsigned x6 = cvt_pk_bf16(s1[12], s1[13]), x7 = cvt_pk_bf16(s1[14], s1[15]);
        plane32_swap(x0, x2); plane32_swap(x1, x3);
        plane32_swap(x4, x6); plane32_swap(x5, x7);
        uint4v f2 = {x0, x1, x2, x3};
        uint4v f3 = {x4, x5, x6, x7};

        bf16x8 pf0 = __builtin_bit_cast(bf16x8, f0);
        bf16x8 pf1 = __builtin_bit_cast(bf16x8, f1);
        bf16x8 pf2 = __builtin_bit_cast(bf16x8, f2);
        bf16x8 pf3 = __builtin_bit_cast(bf16x8, f3);

        __builtin_amdgcn_s_setprio(1);
#pragma unroll
        for (int ks = 0; ks < 4; ++ks) {
            int cpos = ((ks << 1) | hi) ^ rsw;
            bf16x8 pf = (ks == 0) ? pf0 : (ks == 1) ? pf1 : (ks == 2) ? pf2 : pf3;
            bf16x8 v0 = *(const bf16x8*)&Vb[ql * 64 + (cpos << 3)];
            bf16x8 v1 = *(const bf16x8*)&Vb[(32 + ql) * 64 + (cpos << 3)];
            O0 = __builtin_amdgcn_mfma_f32_32x32x16_bf16(pf, v0, O0, 0, 0, 0);
            O1 = __builtin_amdgcn_mfma_f32_32x32x16_bf16(pf, v1, O1, 0, 0, 0);
        }
        __builtin_amdgcn_s_setprio(0);
    };

    // prologue: K(0) + V(0)
    stageK(tbase, 0);
    stageV(tbase);
#pragma unroll 1
    for (int it = 0; it < 8; ++it) {
        if (it < 7) {
            stageK(tbase + ((it + 1) << 6), (it + 1) & 1);
            asm volatile("s_waitcnt vmcnt(4)\n\ts_barrier" ::: "memory");  // K(it)+V(it) ready
        } else {
            asm volatile("s_waitcnt vmcnt(0)\n\ts_barrier" ::: "memory");  // last tile ready
        }
        body(tbase + (it << 6), it & 1);
        __builtin_amdgcn_s_barrier();          // all waves done reading V(it)/K(it)
        if (it < 7) stageV(tbase + ((it + 1) << 6));
    }

    // ---- in-LDS fp32 merge of the two kv-halves ----
    __syncthreads();                                   // all K/V reads done
    float* osh = (float*)&Kls[0][0][0];                // 2 x 2048 floats (16 KB)
    float* mlsh = (float*)&Vls[0][0];                  // 2 x 64 floats
    if (kvh == 1) {
        float* obuf = osh + w4 * 2048;
#pragma unroll
        for (int r = 0; r < 16; ++r) {
            int qrow = (r & 3) + 8 * (r >> 2) + 4 * hi;
            obuf[qrow * 64 + ql] = O0[r];
            obuf[qrow * 64 + 32 + ql] = O1[r];
        }
        if (lane < 32) {
            mlsh[w4 * 64 + ql] = m_r;
            mlsh[w4 * 64 + 32 + ql] = l_r;
        }
    }
    __syncthreads();
    if (kvh == 0) {
        float* obuf = osh + w4 * 2048;
        float m2 = mlsh[w4 * 64 + ql];
        float l2 = mlsh[w4 * 64 + 32 + ql];
        float m = fmaxf(m_r, m2);
        float a1 = v_exp2(m_r - m), a2 = v_exp2(m2 - m);
        float inv = 1.0f / (l_r * a1 + l2 * a2);
        float c1 = a1 * inv, c2 = a2 * inv;
        short* cb = ctx + ((size_t)(b * SS + q0 + w4 * 32)) * DD + h * HDD;
#pragma unroll
        for (int r = 0; r < 16; ++r) {
            int qrow = (r & 3) + 8 * (r >> 2) + 4 * hi;
            float cc1 = __shfl(c1, qrow, 64);
            float cc2 = __shfl(c2, qrow, 64);
            float ob0 = obuf[qrow * 64 + ql];
            float ob1 = obuf[qrow * 64 + 32 + ql];
            cb[(size_t)qrow * DD + ql]      = f2bf(O0[r] * cc1 + ob0 * cc2);
            cb[(size_t)qrow * DD + 32 + ql] = f2bf(O1[r] * cc1 + ob1 * cc2);
        }
    }
}

// ---------------------------------------------------------------------------
extern "C" void kernel_launch(void* const* d_in, const int* in_sizes, int n_in,
                              void* d_out, int out_size, void* d_ws, size_t ws_size,
                              hipStream_t stream) {
    const float* h    = (const float*)d_in[0];
    const float* mask = (const float*)d_in[1];
    const float* wq   = (const float*)d_in[2];
    const float* bq   = (const float*)d_in[3];
    const float* wk   = (const float*)d_in[4];
    const float* bk   = (const float*)d_in[5];
    const float* wv   = (const float*)d_in[6];
    const float* bv   = (const float*)d_in[7];
    const float* wo   = (const float*)d_in[8];
    const float* bo   = (const float*)d_in[9];
    float* out = (float*)d_out;

    char* base = (char*)d_ws;
    short* x_bf  = (short*)base;                       // 4 MB @ 0
    short* w_bf  = (short*)(base + (4u << 20));        // 8 MB @ 4
    short* q_bf  = (short*)(base + (12u << 20));       // 4 MB @ 12
    short* k_bf  = (short*)(base + (16u << 20));       // 4 MB @ 16
    short* v_t   = (short*)(base + (20u << 20));       // 4 MB @ 20
    short* ctxbf = (short*)(base + (24u << 20));       // 4 MB @ 24

    k_prep<<<3072, 256, 0, stream>>>(h, wq, wk, wv, wo, x_bf, w_bf);

    dim3 gqkv(DD / QBN, BB * SS / QBM, 3);
    k_gemm_qkv<<<gqkv, 256, 0, stream>>>(x_bf, w_bf, bq, bk, bv, q_bf, k_bf, v_t);

    dim3 gattn(BB * HH, SS / 64);    // bh fastest -> XCD locality; 512 blocks
    k_attn<<<gattn, 256, 0, stream>>>(q_bf, k_bf, v_t, mask, ctxbf);

    dim3 gout(DD / ON, BB * SS / OM);
    k_gemm_out<<<gout, 256, 0, stream>>>(ctxbf, w_bf + (size_t)3 * DD * DD, bo, out);
}